// Round 4
// baseline (619.395 us; speedup 1.0000x reference)
//
#include <hip/hip_runtime.h>
#include <hip/hip_bf16.h>

#define NN 50000     // nodes
#define NR 4         // relations
#define NE 160000    // edges per relation
#define HD 128       // hidden dim
#define OD 100       // out dim
#define NQ 8192      // queries
#define NB_SCAN 196  // 196*256 >= NN

typedef __attribute__((ext_vector_type(8))) short bf16x8;
typedef __attribute__((ext_vector_type(4))) float f32x4;
typedef __attribute__((ext_vector_type(4))) int int4v;

static __device__ __forceinline__ unsigned short f2bf(float f) {
    union { float f; unsigned int u; } v; v.f = f;
    unsigned int u = v.u;
    unsigned int r = u + 0x7FFFu + ((u >> 16) & 1u);   // RNE
    return (unsigned short)(r >> 16);
}
static __device__ __forceinline__ float bflo(unsigned int v) {
    union { unsigned int u; float f; } x; x.u = v << 16; return x.f;
}
static __device__ __forceinline__ float bfhi(unsigned int v) {
    union { unsigned int u; float f; } x; x.u = v & 0xffff0000u; return x.f;
}

// ---------------- graph preprocessing ----------------

__global__ void zero_deg_kernel(int* __restrict__ deg) {
    int i = blockIdx.x * 256 + threadIdx.x;
    if (i < NR * NN) deg[i] = 0;
}

__global__ void count_deg_kernel(const int* __restrict__ edge_dst, int* __restrict__ deg) {
    int i = blockIdx.x * 256 + threadIdx.x;
    if (i < NR * NE) {
        int r = i / NE;
        atomicAdd(&deg[r * NN + edge_dst[i]], 1);
    }
}

__global__ __launch_bounds__(256) void scanA_kernel(const int* __restrict__ deg,
                                                    int* __restrict__ excl,
                                                    int* __restrict__ bsum) {
    const int r = blockIdx.x / NB_SCAN;
    const int b = blockIdx.x % NB_SCAN;
    const int tid = threadIdx.x;
    const int idx = b * 256 + tid;
    int v = (idx < NN) ? deg[r * NN + idx] : 0;
    __shared__ int buf[256];
    buf[tid] = v; __syncthreads();
    int sum = v;
    for (int off = 1; off < 256; off <<= 1) {
        int t = (tid >= off) ? buf[tid - off] : 0;
        __syncthreads();
        sum += t; buf[tid] = sum;
        __syncthreads();
    }
    if (idx < NN) excl[r * NN + idx] = sum - v;
    if (tid == 255) bsum[r * NB_SCAN + b] = sum;
}

__global__ __launch_bounds__(256) void scanB_kernel(int* __restrict__ bsum) {
    const int r = blockIdx.x;
    const int tid = threadIdx.x;
    int v = (tid < NB_SCAN) ? bsum[r * NB_SCAN + tid] : 0;
    __shared__ int buf[256];
    buf[tid] = v; __syncthreads();
    int sum = v;
    for (int off = 1; off < 256; off <<= 1) {
        int t = (tid >= off) ? buf[tid - off] : 0;
        __syncthreads();
        sum += t; buf[tid] = sum;
        __syncthreads();
    }
    if (tid < NB_SCAN) bsum[r * NB_SCAN + tid] = sum - v;
}

__global__ __launch_bounds__(256) void scanC_kernel(const int* __restrict__ excl,
                                                    const int* __restrict__ bsum,
                                                    int* __restrict__ row_start,
                                                    int* __restrict__ cursor) {
    const int r = blockIdx.x / NB_SCAN;
    const int b = blockIdx.x % NB_SCAN;
    const int idx = b * 256 + threadIdx.x;
    if (idx < NN) {
        int v = excl[r * NN + idx] + bsum[r * NB_SCAN + b];
        row_start[r * (NN + 1) + idx] = v;
        cursor[r * NN + idx] = v;
    }
    if (b == 0 && threadIdx.x == 0) row_start[r * (NN + 1) + NN] = NE;
}

__global__ void fill_csr_kernel(const int* __restrict__ edge_src,
                                const int* __restrict__ edge_dst,
                                int* __restrict__ cursor, int* __restrict__ csr_src) {
    int i = blockIdx.x * 256 + threadIdx.x;
    if (i < NR * NE) {
        int r = i / NE;
        int dst = edge_dst[i];
        int pos = atomicAdd(&cursor[r * NN + dst], 1);
        csr_src[r * NE + pos] = edge_src[i];
    }
}

__global__ void inv_deg_kernel(const int* __restrict__ deg, float* __restrict__ inv) {
    int i = blockIdx.x * 256 + threadIdx.x;
    if (i < NR * NN) inv[i] = 1.0f / fmaxf((float)deg[i], 1.0f);
}

// ---------------- weight / feature prep ----------------

__global__ void conv_feat_kernel(const float* __restrict__ f, unsigned short* __restrict__ h) {
    int i = (blockIdx.x * 256 + threadIdx.x) * 4;
    if (i < NN * HD) {
        h[i + 0] = f2bf(f[i + 0]);
        h[i + 1] = f2bf(f[i + 1]);
        h[i + 2] = f2bf(f[i + 2]);
        h[i + 3] = f2bf(f[i + 3]);
    }
}

// WtH [128 cols][640 k] bf16: k<128 -> Ws[k][c]; k=128+r*128+kk -> Wr[r][kk][c]
__global__ void prep_wh_kernel(const float* __restrict__ Ws, const float* __restrict__ Wr,
                               unsigned short* __restrict__ Wt) {
    int c = blockIdx.x;     // 128
    int k = threadIdx.x;    // 640
    float v;
    if (k < HD) v = Ws[k * HD + c];
    else {
        int r = (k - HD) >> 7, kk = (k - HD) & 127;
        v = Wr[(r * HD + kk) * HD + c];
    }
    Wt[c * (NR + 1) * HD + k] = f2bf(v);
}

// WtO [128 cols][640 k] bf16: cols >= 100 are zero
__global__ void prep_wo_kernel(const float* __restrict__ Ws, const float* __restrict__ Wr,
                               unsigned short* __restrict__ Wt) {
    int c = blockIdx.x;     // 128
    int k = threadIdx.x;    // 640
    float v = 0.0f;
    if (c < OD) {
        if (k < HD) v = Ws[k * OD + c];
        else {
            int r = (k - HD) >> 7, kk = (k - HD) & 127;
            v = Wr[(r * HD + kk) * OD + c];
        }
    }
    Wt[c * (NR + 1) * HD + k] = f2bf(v);
}

// ---------------- fused: agg-in-LDS + GEMM ----------------
// Block = 32 nodes, 256 threads = 4 waves. Wave w = relation w.
// Phase 1: stage h tile (32x256B) in LDS; wave r walks its contiguous CSR strip
//          for nodes [m0, m0+32), gathering h[src] rows (256B across wave) and
//          emitting inv_deg-scaled bf16 rows into the LDS agg tile [32][512].
// Phase 2: GEMM [hT | agg](32x640) @ Wt(128x640)^T -> out 32x128.
//          A from LDS (XOR swizzle (row&7)<<4); B fragments direct from global
//          (Wt = 160KB, L2-resident); no barriers inside K-loop.
// MODE 0: relu + bf16 out via LDS bounce.  MODE 1: f32 direct out.

template<int MODE>
__global__ __launch_bounds__(256, 4)
void fused_kernel(const unsigned short* __restrict__ h,
                  const unsigned short* __restrict__ Bt,
                  const int* __restrict__ row_start,
                  const int* __restrict__ csr_src,
                  const float* __restrict__ inv_deg,
                  void* __restrict__ outp, int M) {
    __shared__ __align__(16) char lds[40960];   // [0,8192) hT ; [8192,40960) agg [32][1024B]
    const int tid = threadIdx.x;
    const int m0 = blockIdx.x * 32;
    const int lane = tid & 63;
    const int w = tid >> 6;

    // ---- stage h tile: 32 rows x 256B = 512 x 16B chunks, 2 per thread ----
#pragma unroll
    for (int i = 0; i < 2; i++) {
        const int c = tid + i * 256;
        const int row = c >> 4, kb = (c & 15) * 16;
        int gr = m0 + row; if (gr >= M) gr = M - 1;
        int4v v = *(const int4v*)((const char*)h + (size_t)gr * 256 + kb);
        *(int4v*)(lds + row * 256 + (kb ^ ((row & 7) << 4))) = v;
    }

    // ---- gather phase: wave w = relation r over nodes [m0, m0+nCnt) ----
    {
        const int r = w;
        const int nCnt = (M - m0 < 32) ? (M - m0) : 32;
        const int base = r * (NN + 1) + m0;
        const int* __restrict__ csr = csr_src + r * NE;
        const char* hp = (const char*)h + lane * 4;

        int n = 0;
        float s0 = 0.f, s1 = 0.f;
        int t = row_start[base];
        const int tEnd = row_start[base + nCnt];
        int e = row_start[base + 1];

        auto emitRow = [&]() {
            const float wd = inv_deg[r * NN + m0 + n];
            unsigned int p = (unsigned int)f2bf(wd * s0) |
                             ((unsigned int)f2bf(wd * s1) << 16);
            *(unsigned int*)(lds + 8192 + n * 1024 +
                             ((r * 256 + lane * 4) ^ ((n & 7) << 4))) = p;
            s0 = 0.f; s1 = 0.f; ++n;
        };

        unsigned int v0 = 0, v1 = 0;
        if (t < tEnd) {
            int src = __builtin_amdgcn_readfirstlane(csr[t]);
            v0 = *(const unsigned int*)(hp + (size_t)src * 256);
        }
        if (t + 1 < tEnd) {
            int src = __builtin_amdgcn_readfirstlane(csr[t + 1]);
            v1 = *(const unsigned int*)(hp + (size_t)src * 256);
        }
        while (t < tEnd) {
            while (t >= e) { emitRow(); e = row_start[base + n + 1]; }
            s0 += bflo(v0); s1 += bfhi(v0);
            v0 = v1;
            if (t + 2 < tEnd) {
                int src = __builtin_amdgcn_readfirstlane(csr[t + 2]);
                v1 = *(const unsigned int*)(hp + (size_t)src * 256);
            }
            ++t;
        }
        while (n < nCnt) emitRow();
        for (int z = nCnt; z < 32; ++z)
            *(unsigned int*)(lds + 8192 + z * 1024 +
                             ((r * 256 + lane * 4) ^ ((z & 7) << 4))) = 0u;
    }
    __syncthreads();

    // ---- GEMM phase: 4 waves = 4 N-groups of 32 cols; wave tile 32M x 32N ----
    const int lr = lane & 15;
    const int lg = lane >> 4;
    const int wn = w * 32;
    const char* bB = (const char*)Bt;

    f32x4 acc[2][2];
#pragma unroll
    for (int mi = 0; mi < 2; mi++)
#pragma unroll
        for (int ni = 0; ni < 2; ni++) acc[mi][ni] = (f32x4){0.f, 0.f, 0.f, 0.f};

#pragma unroll
    for (int ks = 0; ks < 10; ++ks) {
#pragma unroll
        for (int ksub = 0; ksub < 2; ++ksub) {
            bf16x8 af[2], bfr[2];
#pragma unroll
            for (int mi = 0; mi < 2; mi++) {
                const int row = mi * 16 + lr;
                int lo;
                if (ks < 2)
                    lo = row * 256 + ((ks * 128 + ksub * 64 + lg * 16) ^ ((row & 7) << 4));
                else
                    lo = 8192 + row * 1024 +
                         (((ks - 2) * 128 + ksub * 64 + lg * 16) ^ ((row & 7) << 4));
                af[mi] = *(const bf16x8*)(lds + lo);
            }
#pragma unroll
            for (int ni = 0; ni < 2; ni++) {
                const int col = wn + ni * 16 + lr;
                bfr[ni] = *(const bf16x8*)(bB + col * 1280 + ks * 128 + ksub * 64 + lg * 16);
            }
#pragma unroll
            for (int mi = 0; mi < 2; mi++)
#pragma unroll
                for (int ni = 0; ni < 2; ni++)
                    acc[mi][ni] = __builtin_amdgcn_mfma_f32_16x16x32_bf16(af[mi], bfr[ni], acc[mi][ni], 0, 0, 0);
        }
    }

    if (MODE == 0) {
        __syncthreads();                      // all waves done reading hT
#pragma unroll
        for (int mi = 0; mi < 2; mi++)
#pragma unroll
            for (int ni = 0; ni < 2; ni++) {
                const int col = wn + ni * 16 + lr;
#pragma unroll
                for (int j = 0; j < 4; j++) {
                    const int row = mi * 16 + lg * 4 + j;
                    *(unsigned short*)(lds + row * 256 + col * 2) =
                        f2bf(fmaxf(acc[mi][ni][j], 0.f));
                }
            }
        __syncthreads();
        unsigned short* o = (unsigned short*)outp;
#pragma unroll
        for (int i = 0; i < 2; i++) {
            const int c = tid + i * 256;
            const int row = c >> 4, kb = (c & 15) * 16;
            const int grow = m0 + row;
            if (grow < M)
                *(int4v*)((char*)o + (size_t)grow * 256 + kb) = *(const int4v*)(lds + row * 256 + kb);
        }
    } else {
        float* o = (float*)outp;
#pragma unroll
        for (int mi = 0; mi < 2; mi++)
#pragma unroll
            for (int ni = 0; ni < 2; ni++) {
                const int col = wn + ni * 16 + lr;
#pragma unroll
                for (int j = 0; j < 4; j++) {
                    const int row = m0 + mi * 16 + lg * 4 + j;
                    if (row < M) o[(size_t)row * 128 + col] = acc[mi][ni][j];
                }
            }
    }
}

// ---------------- final gather (float4) ----------------

__global__ __launch_bounds__(256) void gather_out_kernel(const float* __restrict__ hOut,
                                                         const int* __restrict__ head,
                                                         const int* __restrict__ tail,
                                                         float* __restrict__ out) {
    const int gid = blockIdx.x * 256 + threadIdx.x;
    const int q = gid >> 5, c = gid & 31;
    if (q >= 2 * NQ || c >= 25) return;
    const int node = (q < NQ) ? head[q] : tail[q - NQ];
    f32x4 v = *(const f32x4*)(hOut + (size_t)node * 128 + c * 4);
    *(f32x4*)(out + (size_t)q * OD + c * 4) = v;
}

// ---------------- launch ----------------

extern "C" void kernel_launch(void* const* d_in, const int* in_sizes, int n_in,
                              void* d_out, int out_size, void* d_ws, size_t ws_size,
                              hipStream_t stream) {
    const float* feature = (const float*)d_in[0];
    const float* Wr_h    = (const float*)d_in[1];   // [2][4][128][128]
    const float* Ws_h    = (const float*)d_in[2];   // [2][128][128]
    const float* Wr_o    = (const float*)d_in[3];   // [4][128][100]
    const float* Ws_o    = (const float*)d_in[4];   // [128][100]
    const int* edge_src  = (const int*)d_in[5];
    const int* edge_dst  = (const int*)d_in[6];
    const int* head_idx  = (const int*)d_in[7];
    const int* tail_idx  = (const int*)d_in[8];
    float* out = (float*)d_out;

    char* ws = (char*)d_ws;
    size_t off = 0;
    auto alloc = [&](size_t bytes) -> void* {
        void* p = ws + off;
        off += (bytes + 255) & ~(size_t)255;
        return p;
    };
    unsigned short* hA   = (unsigned short*)alloc((size_t)NN * HD * 2);
    unsigned short* hB   = (unsigned short*)alloc((size_t)NN * HD * 2);
    float*          hOut = (float*)alloc((size_t)NN * 128 * 4);
    unsigned short* WtH0 = (unsigned short*)alloc(128 * 640 * 2);
    unsigned short* WtH1 = (unsigned short*)alloc(128 * 640 * 2);
    unsigned short* WtO  = (unsigned short*)alloc(128 * 640 * 2);
    int*            deg  = (int*)alloc((size_t)NR * NN * 4);
    float*          inv  = (float*)alloc((size_t)NR * NN * 4);
    int*            rowS = (int*)alloc((size_t)NR * (NN + 1) * 4);
    int*            curs = (int*)alloc((size_t)NR * NN * 4);
    int*            csrS = (int*)alloc((size_t)NR * NE * 4);
    int*            excl = (int*)alloc((size_t)NR * NN * 4);
    int*            bsum = (int*)alloc((size_t)NR * NB_SCAN * 4);
    (void)ws_size;

    // graph prep
    zero_deg_kernel<<<(NR * NN + 255) / 256, 256, 0, stream>>>(deg);
    count_deg_kernel<<<(NR * NE + 255) / 256, 256, 0, stream>>>(edge_dst, deg);
    scanA_kernel<<<NR * NB_SCAN, 256, 0, stream>>>(deg, excl, bsum);
    scanB_kernel<<<NR, 256, 0, stream>>>(bsum);
    scanC_kernel<<<NR * NB_SCAN, 256, 0, stream>>>(excl, bsum, rowS, curs);
    fill_csr_kernel<<<(NR * NE + 255) / 256, 256, 0, stream>>>(edge_src, edge_dst, curs, csrS);
    inv_deg_kernel<<<(NR * NN + 255) / 256, 256, 0, stream>>>(deg, inv);

    // weight / feature prep
    conv_feat_kernel<<<(NN * HD / 4 + 255) / 256, 256, 0, stream>>>(feature, hA);
    prep_wh_kernel<<<128, 640, 0, stream>>>(Ws_h, Wr_h, WtH0);
    prep_wh_kernel<<<128, 640, 0, stream>>>(Ws_h + HD * HD, Wr_h + NR * HD * HD, WtH1);
    prep_wo_kernel<<<128, 640, 0, stream>>>(Ws_o, Wr_o, WtO);

    const int fblocks = (NN + 31) / 32;   // 1563

    fused_kernel<0><<<fblocks, 256, 0, stream>>>(hA, WtH0, rowS, csrS, inv, hB, NN);
    fused_kernel<0><<<fblocks, 256, 0, stream>>>(hB, WtH1, rowS, csrS, inv, hA, NN);
    fused_kernel<1><<<fblocks, 256, 0, stream>>>(hA, WtO,  rowS, csrS, inv, hOut, NN);

    gather_out_kernel<<<(2 * NQ * 32 + 255) / 256, 256, 0, stream>>>(hOut, head_idx, tail_idx, out);
}